// Round 2
// baseline (265.872 us; speedup 1.0000x reference)
//
#include <hip/hip_runtime.h>

// Mobius addition broadcast: out[m,n,:] = a(m,n)*B[n,:] + c(m,n)*x[m,:]
//   a = (1 + 2*xy + nx) / denom,  c = (1 - nB) / denom,
//   denom = 1 + 2*xy + nB*nx,  xy = <x[m], B[n]>
// M=2048, N=1024, D=128 fp32. Output 1.07 GB -> write-BW bound.
// Two-phase: (1) compute per-pair (a,c) into 16 MB workspace (compute-bound,
// ~5 us); (2) pure streaming kernel with no shuffles / no division.

#define M_DIM 2048
#define N_DIM 1024
#define D_DIM 128
#define NPAIRS ((long long)M_DIM * N_DIM)

using f4 = __attribute__((ext_vector_type(4))) float;
using f2 = __attribute__((ext_vector_type(2))) float;

__device__ __forceinline__ float dot4(f4 u, f4 v) {
    return u.x * v.x + u.y * v.y + u.z * v.z + u.w * v.w;
}

// ---------------- Phase 1: per-pair coefficients ----------------
// Grid: (N/64, M/64) blocks of 256 threads; each thread owns a 4m x 4n tile.
__global__ __launch_bounds__(256) void coef_kernel(
    const float* __restrict__ B, const float* __restrict__ x,
    f2* __restrict__ sr)
{
    const int tx = threadIdx.x & 15;        // n within tile
    const int ty = threadIdx.x >> 4;        // m within tile
    const int m0 = blockIdx.y * 64 + ty * 4;
    const int n0 = blockIdx.x * 64 + tx * 4;

    float acc[4][4] = {};
    float anx[4] = {};
    float anb[4] = {};

    for (int d = 0; d < D_DIM; d += 4) {
        f4 xa[4], ba[4];
        #pragma unroll
        for (int i = 0; i < 4; ++i)
            xa[i] = *reinterpret_cast<const f4*>(x + (long long)(m0 + i) * D_DIM + d);
        #pragma unroll
        for (int j = 0; j < 4; ++j)
            ba[j] = *reinterpret_cast<const f4*>(B + (long long)(n0 + j) * D_DIM + d);
        #pragma unroll
        for (int i = 0; i < 4; ++i) anx[i] += dot4(xa[i], xa[i]);
        #pragma unroll
        for (int j = 0; j < 4; ++j) anb[j] += dot4(ba[j], ba[j]);
        #pragma unroll
        for (int i = 0; i < 4; ++i)
            #pragma unroll
            for (int j = 0; j < 4; ++j)
                acc[i][j] += dot4(xa[i], ba[j]);
    }

    #pragma unroll
    for (int i = 0; i < 4; ++i) {
        #pragma unroll
        for (int j = 0; j < 4; ++j) {
            const float xy    = acc[i][j];
            const float denom = 1.0f + 2.0f * xy + anb[j] * anx[i];
            const float rd    = 1.0f / denom;
            f2 v;
            v.x = (1.0f + 2.0f * xy + anx[i]) * rd;   // a
            v.y = (1.0f - anb[j]) * rd;               // c
            sr[(long long)(m0 + i) * N_DIM + (n0 + j)] = v;
        }
    }
}

// ---------------- Phase 2: streaming write ----------------
// Half-wave (32 lanes) per (m,n) pair; lane i handles d = 4i..4i+3.
__global__ __launch_bounds__(256) void stream_kernel(
    const float* __restrict__ B, const float* __restrict__ x,
    const f2* __restrict__ sr, float* __restrict__ out)
{
    const int lane = threadIdx.x & 31;
    const long long hw  = ((long long)blockIdx.x * blockDim.x + threadIdx.x) >> 5;
    const long long nhw = ((long long)gridDim.x * blockDim.x) >> 5;

    for (long long p = hw; p < NPAIRS; p += nhw) {
        const int m = (int)(p >> 10);        // N = 1024
        const int n = (int)(p & (N_DIM - 1));

        const f2 ac = sr[p];
        const f4 bv = *reinterpret_cast<const f4*>(B + (long long)n * D_DIM + lane * 4);
        const f4 xv = *reinterpret_cast<const f4*>(x + (long long)m * D_DIM + lane * 4);

        f4 o;
        o.x = ac.x * bv.x + ac.y * xv.x;
        o.y = ac.x * bv.y + ac.y * xv.y;
        o.z = ac.x * bv.z + ac.y * xv.z;
        o.w = ac.x * bv.w + ac.y * xv.w;

        __builtin_nontemporal_store(o,
            reinterpret_cast<f4*>(out + p * D_DIM + lane * 4));
    }
}

// ---------------- Fallback (r1 kernel) if ws is too small ----------------
__global__ __launch_bounds__(256) void mobius_fused_kernel(
    const float* __restrict__ B, const float* __restrict__ x,
    float* __restrict__ out)
{
    const int lane = threadIdx.x & 31;
    const long long hw  = ((long long)blockIdx.x * blockDim.x + threadIdx.x) >> 5;
    const long long nhw = ((long long)gridDim.x * blockDim.x) >> 5;

    for (long long p = hw; p < NPAIRS; p += nhw) {
        const int m = (int)(p >> 10);
        const int n = (int)(p & (N_DIM - 1));
        const f4 xv = *reinterpret_cast<const f4*>(x + (long long)m * D_DIM + lane * 4);
        const f4 bv = *reinterpret_cast<const f4*>(B + (long long)n * D_DIM + lane * 4);
        float xy = dot4(xv, bv), sxx = dot4(xv, xv), sbb = dot4(bv, bv);
        #pragma unroll
        for (int off = 1; off < 32; off <<= 1) {
            xy  += __shfl_xor(xy,  off, 64);
            sxx += __shfl_xor(sxx, off, 64);
            sbb += __shfl_xor(sbb, off, 64);
        }
        const float coefB = 1.0f + 2.0f * xy + sxx;
        const float coefx = 1.0f - sbb;
        const float r     = 1.0f / (1.0f + 2.0f * xy + sbb * sxx);
        f4 o;
        o.x = (coefB * bv.x + coefx * xv.x) * r;
        o.y = (coefB * bv.y + coefx * xv.y) * r;
        o.z = (coefB * bv.z + coefx * xv.z) * r;
        o.w = (coefB * bv.w + coefx * xv.w) * r;
        __builtin_nontemporal_store(o,
            reinterpret_cast<f4*>(out + p * D_DIM + lane * 4));
    }
}

extern "C" void kernel_launch(void* const* d_in, const int* in_sizes, int n_in,
                              void* d_out, int out_size, void* d_ws, size_t ws_size,
                              hipStream_t stream) {
    const float* B = (const float*)d_in[0];   // [N, D]
    const float* x = (const float*)d_in[1];   // [M, D]
    float* out = (float*)d_out;               // [M, N, D]

    const size_t need = (size_t)NPAIRS * sizeof(f2);   // 16 MB
    if (ws_size >= need) {
        f2* sr = (f2*)d_ws;
        dim3 g1(N_DIM / 64, M_DIM / 64);               // 16 x 32 = 512 blocks
        coef_kernel<<<g1, 256, 0, stream>>>(B, x, sr);
        stream_kernel<<<2048, 256, 0, stream>>>(B, x, sr, out);
    } else {
        mobius_fused_kernel<<<2048, 256, 0, stream>>>(B, x, out);
    }
}